// Round 3
// baseline (915.051 us; speedup 1.0000x reference)
//
#include <hip/hip_runtime.h>
#include <hip/hip_bf16.h>

#define NHEADS 12
#define HDIM 64
#define BATCH 2
#define SEQ 2048
#define DMODEL 768
#define MROWS (BATCH * SEQ)   // 4096

typedef __bf16  bf16x8 __attribute__((ext_vector_type(8)));
typedef float   f32x4  __attribute__((ext_vector_type(4)));
typedef unsigned short ushort_t;

__device__ inline unsigned short to_bf16(float f) {
    union { float f; unsigned u; } x; x.f = f;
    const unsigned r = x.u + 0x7FFFu + ((x.u >> 16) & 1u);   // RNE
    return (unsigned short)(r >> 16);
}

// async global->LDS, 16B per lane, dest = wave-uniform base + lane*16
#define GLDS16(gsrc, ldst)                                                    \
    __builtin_amdgcn_global_load_lds(                                         \
        (const __attribute__((address_space(1))) void*)(gsrc),                \
        (__attribute__((address_space(3))) void*)(ldst), 16, 0, 0)

// ---------------------------------------------------------------------------
// cvt_x: fp32 -> bf16 elementwise (x, 3.1M elements), float4-vectorized
// ---------------------------------------------------------------------------
__global__ __launch_bounds__(256) void cvt_x(const float* __restrict__ in,
                                             unsigned short* __restrict__ out,
                                             int n4) {
    const int i = blockIdx.x * 256 + threadIdx.x;
    if (i < n4) {
        const float4 v = reinterpret_cast<const float4*>(in)[i];
        ushort4 o;
        o.x = to_bf16(v.x); o.y = to_bf16(v.y);
        o.z = to_bf16(v.z); o.w = to_bf16(v.w);
        reinterpret_cast<ushort4*>(out)[i] = o;
    }
}

// ---------------------------------------------------------------------------
// cvt_wT: W (768x768 fp32, [k][n]) -> Wt (768x768 bf16, [n][k]), 4 matrices
// blockIdx.z selects Wq/Wk/Wv/Wo. 32x32 LDS tile transpose, coalesced both sides.
// ---------------------------------------------------------------------------
__global__ __launch_bounds__(256) void cvt_wT(const float* __restrict__ Wq,
                                              const float* __restrict__ Wk,
                                              const float* __restrict__ Wv,
                                              const float* __restrict__ Wo,
                                              unsigned short* __restrict__ wt_all,
                                              unsigned short* __restrict__ wot) {
    const int z = blockIdx.z;
    const float* W = (z == 0) ? Wq : (z == 1) ? Wk : (z == 2) ? Wv : Wo;
    unsigned short* out = (z < 3) ? (wt_all + (size_t)z * DMODEL * DMODEL) : wot;

    __shared__ float tile[32][33];
    const int tx = threadIdx.x & 31, ty = threadIdx.x >> 5;   // ty: 0..7
    const int nbase = blockIdx.x * 32, kbase = blockIdx.y * 32;

    #pragma unroll
    for (int p = 0; p < 4; ++p) {
        const int r = ty + p * 8;
        tile[r][tx] = W[(size_t)(kbase + r) * DMODEL + nbase + tx];
    }
    __syncthreads();
    #pragma unroll
    for (int p = 0; p < 4; ++p) {
        const int r = ty + p * 8;   // local n
        out[(size_t)(nbase + r) * DMODEL + kbase + tx] = to_bf16(tile[tx][r]);
    }
}

// ---------------------------------------------------------------------------
// bf16 MFMA GEMM: C = A (M x 768 bf16) @ Bt^T + bias, Bt is (768 x 768 bf16, [n][k]).
// 128x128 tile, BK=32, 256 threads = 4 waves (2x2), each wave 64x64 via 4x4
// frags of mfma_f32_16x16x32_bf16. global_load_lds(16B) staging, linear LDS
// dest + XOR-swizzled global source; same swizzle on ds_read (rule #21).
// OUT_MODE 0: scatter fp32 to (B,H,S,hd). OUT_MODE 1: fp32 row-major (M x 768).
// ---------------------------------------------------------------------------
template <int OUT_MODE>
__global__ __launch_bounds__(256) void gemm_mfma(const unsigned short* __restrict__ A,
                                                 const unsigned short* __restrict__ Bt,
                                                 const float* __restrict__ bias,
                                                 float* __restrict__ out) {
    constexpr int K = DMODEL;
    __shared__ unsigned short As[128 * 32];   // 8 KB, [row][k] linear + src swizzle
    __shared__ unsigned short Bs[128 * 32];   // 8 KB, [n][k]

    const int t = threadIdx.x;
    const int lane = t & 63;
    const int w = t >> 6, wr = w >> 1, wc = w & 1;
    const int m0 = blockIdx.y * 128, n0 = blockIdx.x * 128;
    const int lr = lane & 15;      // frag row (A) / col (B) / C col
    const int kg = lane >> 4;      // k-group 0..3 (8 bf16 each) / C row group

    // staging: 512 chunks of 16B per tile; thread t covers chunks t and t+256.
    // stored chunk cp at row holds logical chunk c = cp ^ ((row>>1)&3).
    const int row0 = t >> 2,        cp0 = t & 3;
    const int row1 = (t + 256) >> 2, cp1 = t & 3;
    const int c0 = cp0 ^ ((row0 >> 1) & 3);
    const int c1 = cp1 ^ ((row1 >> 1) & 3);
    unsigned short* asd0 = &As[(w * 64) * 8];          // wave-uniform dests
    unsigned short* asd1 = &As[(256 + w * 64) * 8];
    unsigned short* bsd0 = &Bs[(w * 64) * 8];
    unsigned short* bsd1 = &Bs[(256 + w * 64) * 8];

    f32x4 acc[4][4] = {};

    for (int k0 = 0; k0 < K; k0 += 32) {
        GLDS16(A  + (size_t)(m0 + row0) * K + k0 + c0 * 8, asd0);
        GLDS16(A  + (size_t)(m0 + row1) * K + k0 + c1 * 8, asd1);
        GLDS16(Bt + (size_t)(n0 + row0) * K + k0 + c0 * 8, bsd0);
        GLDS16(Bt + (size_t)(n0 + row1) * K + k0 + c1 * 8, bsd1);
        __syncthreads();   // drains vmcnt (compiler-inserted)

        bf16x8 af[4], bfr[4];
        #pragma unroll
        for (int i = 0; i < 4; ++i) {
            const int ar = wr * 64 + i * 16 + lr;
            af[i] = *reinterpret_cast<const bf16x8*>(
                &As[ar * 32 + ((kg ^ ((ar >> 1) & 3)) * 8)]);
            const int br = wc * 64 + i * 16 + lr;
            bfr[i] = *reinterpret_cast<const bf16x8*>(
                &Bs[br * 32 + ((kg ^ ((br >> 1) & 3)) * 8)]);
        }
        #pragma unroll
        for (int i = 0; i < 4; ++i)
            #pragma unroll
            for (int j = 0; j < 4; ++j)
                acc[i][j] = __builtin_amdgcn_mfma_f32_16x16x32_bf16(
                    af[i], bfr[j], acc[i][j], 0, 0, 0);
        __syncthreads();
    }

    // epilogue: C/D layout col=lane&15, row=(lane>>4)*4+reg  [m89/m91 verified]
    const int mb = m0 + wr * 64, nb = n0 + wc * 64;
    #pragma unroll
    for (int i = 0; i < 4; ++i) {
        #pragma unroll
        for (int j = 0; j < 4; ++j) {
            const int col = nb + j * 16 + lr;
            const float bv = bias[col];
            #pragma unroll
            for (int q = 0; q < 4; ++q) {
                const int row = mb + i * 16 + kg * 4 + q;
                const float val = acc[i][j][q] + bv;
                if (OUT_MODE == 0) {
                    const int b = row >> 11, s = row & (SEQ - 1);
                    const int h = col >> 6, d = col & (HDIM - 1);
                    out[(((size_t)(b * NHEADS + h)) * SEQ + s) * HDIM + d] = val;
                } else {
                    out[(size_t)row * DMODEL + col] = val;
                }
            }
        }
    }
}

// ---------------------------------------------------------------------------
// Flash attention fp32 (unchanged structure): one block per (64 q-rows, b*h).
// Q/K/V fp32 in (B,H,S,hd). Output context written BF16 as (B, S, H*hd).
// ---------------------------------------------------------------------------
__global__ __launch_bounds__(256) void flash64(const float* __restrict__ Q,
                                               const float* __restrict__ Kg,
                                               const float* __restrict__ Vg,
                                               unsigned short* __restrict__ Cctx) {
    __shared__ float q_s[64][65];
    __shared__ float k_s[64][65];
    __shared__ float v_s[64][65];
    __shared__ float p_s[64][65];
    __shared__ float f_sh[64], l_sh[64];

    const int t = threadIdx.x;
    const int qb = blockIdx.x;   // 0..31
    const int bh = blockIdx.y;   // 0..23
    const int tx = t & 15, ty = t >> 4;
    const size_t base = (size_t)bh * SEQ * HDIM;

    #pragma unroll
    for (int i = 0; i < 4; ++i) {
        const int idx = t + 256 * i;
        const int row = idx >> 4, c4 = (idx & 15) << 2;
        const float4 v = *reinterpret_cast<const float4*>(
            &Q[base + (size_t)(qb * 64 + row) * HDIM + c4]);
        q_s[row][c4 + 0] = v.x * 0.125f; q_s[row][c4 + 1] = v.y * 0.125f;
        q_s[row][c4 + 2] = v.z * 0.125f; q_s[row][c4 + 3] = v.w * 0.125f;
    }

    float acc[4][4] = {};
    float m_t = -1e30f, l_t = 0.0f;

    for (int kt = 0; kt < SEQ / 64; ++kt) {
        __syncthreads();
        #pragma unroll
        for (int i = 0; i < 4; ++i) {
            const int idx = t + 256 * i;
            const int row = idx >> 4, c4 = (idx & 15) << 2;
            const size_t g = base + (size_t)(kt * 64 + row) * HDIM + c4;
            const float4 kv = *reinterpret_cast<const float4*>(&Kg[g]);
            k_s[row][c4 + 0] = kv.x; k_s[row][c4 + 1] = kv.y;
            k_s[row][c4 + 2] = kv.z; k_s[row][c4 + 3] = kv.w;
            const float4 vv = *reinterpret_cast<const float4*>(&Vg[g]);
            v_s[row][c4 + 0] = vv.x; v_s[row][c4 + 1] = vv.y;
            v_s[row][c4 + 2] = vv.z; v_s[row][c4 + 3] = vv.w;
        }
        __syncthreads();

        float sc[4][4] = {};
        #pragma unroll 8
        for (int d = 0; d < 64; ++d) {
            float a[4], b[4];
            #pragma unroll
            for (int i = 0; i < 4; ++i) a[i] = q_s[ty * 4 + i][d];
            #pragma unroll
            for (int j = 0; j < 4; ++j) b[j] = k_s[tx * 4 + j][d];
            #pragma unroll
            for (int i = 0; i < 4; ++i)
                #pragma unroll
                for (int j = 0; j < 4; ++j)
                    sc[i][j] = fmaf(a[i], b[j], sc[i][j]);
        }
        #pragma unroll
        for (int i = 0; i < 4; ++i)
            #pragma unroll
            for (int j = 0; j < 4; ++j)
                p_s[ty * 4 + i][tx * 4 + j] = sc[i][j];
        __syncthreads();

        if (t < 64) {
            float pm = -1e30f;
            #pragma unroll 8
            for (int j = 0; j < 64; ++j) pm = fmaxf(pm, p_s[t][j]);
            const float mn = fmaxf(m_t, pm);
            const float f = __expf(m_t - mn);
            float ts = 0.0f;
            #pragma unroll 8
            for (int j = 0; j < 64; ++j) {
                const float p = __expf(p_s[t][j] - mn);
                p_s[t][j] = p;
                ts += p;
            }
            l_t = l_t * f + ts;
            m_t = mn;
            f_sh[t] = f;
        }
        __syncthreads();

        float fq[4];
        #pragma unroll
        for (int i = 0; i < 4; ++i) fq[i] = f_sh[ty * 4 + i];
        #pragma unroll
        for (int i = 0; i < 4; ++i)
            #pragma unroll
            for (int j = 0; j < 4; ++j)
                acc[i][j] *= fq[i];
        #pragma unroll 8
        for (int kj = 0; kj < 64; ++kj) {
            float p[4], vv[4];
            #pragma unroll
            for (int i = 0; i < 4; ++i) p[i] = p_s[ty * 4 + i][kj];
            #pragma unroll
            for (int j = 0; j < 4; ++j) vv[j] = v_s[kj][tx * 4 + j];
            #pragma unroll
            for (int i = 0; i < 4; ++i)
                #pragma unroll
                for (int j = 0; j < 4; ++j)
                    acc[i][j] = fmaf(p[i], vv[j], acc[i][j]);
        }
    }

    if (t < 64) l_sh[t] = l_t;
    __syncthreads();

    const int b = bh / NHEADS, h = bh % NHEADS;
    #pragma unroll
    for (int i = 0; i < 4; ++i) {
        const float rl = 1.0f / l_sh[ty * 4 + i];
        const int s = qb * 64 + ty * 4 + i;
        #pragma unroll
        for (int j = 0; j < 4; ++j) {
            Cctx[(((size_t)(b * SEQ + s)) * NHEADS + h) * HDIM + tx * 4 + j] =
                to_bf16(acc[i][j] * rl);
        }
    }
}

// ---------------------------------------------------------------------------
extern "C" void kernel_launch(void* const* d_in, const int* in_sizes, int n_in,
                              void* d_out, int out_size, void* d_ws, size_t ws_size,
                              hipStream_t stream) {
    const float* x  = (const float*)d_in[0];
    const float* Wq = (const float*)d_in[1];
    const float* bq = (const float*)d_in[2];
    const float* Wk = (const float*)d_in[3];
    const float* bk = (const float*)d_in[4];
    const float* Wv = (const float*)d_in[5];
    const float* bv = (const float*)d_in[6];
    const float* Wo = (const float*)d_in[7];
    const float* bo = (const float*)d_in[8];
    float* out = (float*)d_out;

    const size_t MD = (size_t)MROWS * DMODEL;    // 3,145,728
    const size_t W2 = (size_t)DMODEL * DMODEL;   // 589,824
    float* ws = (float*)d_ws;
    float* q_ws = ws;                 // fp32 (B,H,S,hd)
    float* k_ws = ws + MD;
    float* v_ws = ws + 2 * MD;
    unsigned short* bfb    = (unsigned short*)(ws + 3 * MD);
    unsigned short* x_bf   = bfb;          // bf16 x (M x 768)
    unsigned short* c_bf   = bfb;          // bf16 context — ALIASES x_bf (disjoint live ranges)
    unsigned short* wt_all = bfb + MD;     // Wq^T,Wk^T,Wv^T bf16 [n][k]
    unsigned short* wot    = wt_all + 3 * W2;
    // total ws: 3*MD*4 + (MD + 4*W2)*2 = 48.8 MB

    cvt_x<<<(int)(MD / 4 + 255) / 256, 256, 0, stream>>>(x, x_bf, (int)(MD / 4));
    cvt_wT<<<dim3(24, 24, 4), 256, 0, stream>>>(Wq, Wk, Wv, Wo, wt_all, wot);

    dim3 gg(DMODEL / 128, MROWS / 128);   // (6, 32)
    gemm_mfma<0><<<gg, 256, 0, stream>>>(x_bf, wt_all,          bq, q_ws);
    gemm_mfma<0><<<gg, 256, 0, stream>>>(x_bf, wt_all + W2,     bk, k_ws);
    gemm_mfma<0><<<gg, 256, 0, stream>>>(x_bf, wt_all + 2 * W2, bv, v_ws);

    dim3 ga(SEQ / 64, BATCH * NHEADS);    // (32, 24)
    flash64<<<ga, 256, 0, stream>>>(q_ws, k_ws, v_ws, c_bf);

    gemm_mfma<1><<<gg, 256, 0, stream>>>(c_bf, wot, bo, out);
}

// Round 5
// 252.496 us; speedup vs baseline: 3.6240x; 3.6240x over previous
//
#include <hip/hip_runtime.h>
#include <hip/hip_bf16.h>

#define NHEADS 12
#define HDIM 64
#define BATCH 2
#define SEQ 2048
#define DMODEL 768
#define MROWS (BATCH * SEQ)   // 4096

typedef __bf16  bf16x8 __attribute__((ext_vector_type(8)));
typedef float   f32x4  __attribute__((ext_vector_type(4)));

__device__ inline unsigned short to_bf16(float f) {
    union { float f; unsigned u; } x; x.f = f;
    const unsigned r = x.u + 0x7FFFu + ((x.u >> 16) & 1u);   // RNE
    return (unsigned short)(r >> 16);
}
__device__ inline float bf_to_f(unsigned short u) {
    union { unsigned u; float f; } x; x.u = ((unsigned)u) << 16; return x.f;
}

// async global->LDS, 16B per lane, dest = wave-uniform base + lane*16
#define GLDS16(gsrc, ldst)                                                    \
    __builtin_amdgcn_global_load_lds(                                         \
        (const __attribute__((address_space(1))) void*)(gsrc),                \
        (__attribute__((address_space(3))) void*)(ldst), 16, 0, 0)

// ---------------------------------------------------------------------------
// cvt_x: fp32 -> bf16 elementwise, float4-vectorized
// ---------------------------------------------------------------------------
__global__ __launch_bounds__(256) void cvt_x(const float* __restrict__ in,
                                             unsigned short* __restrict__ out,
                                             int n4) {
    const int i = blockIdx.x * 256 + threadIdx.x;
    if (i < n4) {
        const float4 v = reinterpret_cast<const float4*>(in)[i];
        ushort4 o;
        o.x = to_bf16(v.x); o.y = to_bf16(v.y);
        o.z = to_bf16(v.z); o.w = to_bf16(v.w);
        reinterpret_cast<ushort4*>(out)[i] = o;
    }
}

// ---------------------------------------------------------------------------
// cvt_wT: W (768x768 fp32, [k][n]) -> Wt (768x768 bf16, [n][k]), 4 matrices
// ---------------------------------------------------------------------------
__global__ __launch_bounds__(256) void cvt_wT(const float* __restrict__ Wq,
                                              const float* __restrict__ Wk,
                                              const float* __restrict__ Wv,
                                              const float* __restrict__ Wo,
                                              unsigned short* __restrict__ wt_all,
                                              unsigned short* __restrict__ wot) {
    const int z = blockIdx.z;
    const float* W = (z == 0) ? Wq : (z == 1) ? Wk : (z == 2) ? Wv : Wo;
    unsigned short* out = (z < 3) ? (wt_all + (size_t)z * DMODEL * DMODEL) : wot;

    __shared__ float tile[32][33];
    const int tx = threadIdx.x & 31, ty = threadIdx.x >> 5;
    const int nbase = blockIdx.x * 32, kbase = blockIdx.y * 32;

    #pragma unroll
    for (int p = 0; p < 4; ++p) {
        const int r = ty + p * 8;
        tile[r][tx] = W[(size_t)(kbase + r) * DMODEL + nbase + tx];
    }
    __syncthreads();
    #pragma unroll
    for (int p = 0; p < 4; ++p) {
        const int r = ty + p * 8;
        out[(size_t)(nbase + r) * DMODEL + kbase + tx] = to_bf16(tile[tx][r]);
    }
}

// ---------------------------------------------------------------------------
// bf16 MFMA GEMM: C = A (M x 768 bf16) @ Bt^T + bias (then * scale).
// OUT_MODE 0: bf16 scatter to (B,H,S,hd)       (Q, K)
// OUT_MODE 1: fp32 row-major (M x 768)         (final out)
// OUT_MODE 2: bf16 transposed scatter (B,H,hd,S) with packed ushort4 (V^T)
// ---------------------------------------------------------------------------
template <int OUT_MODE>
__global__ __launch_bounds__(256) void gemm_mfma(const unsigned short* __restrict__ A,
                                                 const unsigned short* __restrict__ Bt,
                                                 const float* __restrict__ bias,
                                                 void* __restrict__ outv,
                                                 float scale) {
    constexpr int K = DMODEL;
    __shared__ unsigned short As[128 * 32];
    __shared__ unsigned short Bs[128 * 32];

    const int t = threadIdx.x;
    const int lane = t & 63;
    const int w = t >> 6, wr = w >> 1, wc = w & 1;
    const int m0 = blockIdx.y * 128, n0 = blockIdx.x * 128;
    const int lr = lane & 15;
    const int kg = lane >> 4;

    const int row0 = t >> 2,        cp0 = t & 3;
    const int row1 = (t + 256) >> 2, cp1 = t & 3;
    const int c0 = cp0 ^ ((row0 >> 1) & 3);
    const int c1 = cp1 ^ ((row1 >> 1) & 3);
    unsigned short* asd0 = &As[(w * 64) * 8];
    unsigned short* asd1 = &As[(256 + w * 64) * 8];
    unsigned short* bsd0 = &Bs[(w * 64) * 8];
    unsigned short* bsd1 = &Bs[(256 + w * 64) * 8];

    f32x4 acc[4][4] = {};

    for (int k0 = 0; k0 < K; k0 += 32) {
        GLDS16(A  + (size_t)(m0 + row0) * K + k0 + c0 * 8, asd0);
        GLDS16(A  + (size_t)(m0 + row1) * K + k0 + c1 * 8, asd1);
        GLDS16(Bt + (size_t)(n0 + row0) * K + k0 + c0 * 8, bsd0);
        GLDS16(Bt + (size_t)(n0 + row1) * K + k0 + c1 * 8, bsd1);
        __syncthreads();

        bf16x8 af[4], bfr[4];
        #pragma unroll
        for (int i = 0; i < 4; ++i) {
            const int ar = wr * 64 + i * 16 + lr;
            af[i] = *reinterpret_cast<const bf16x8*>(
                &As[ar * 32 + ((kg ^ ((ar >> 1) & 3)) * 8)]);
            const int br = wc * 64 + i * 16 + lr;
            bfr[i] = *reinterpret_cast<const bf16x8*>(
                &Bs[br * 32 + ((kg ^ ((br >> 1) & 3)) * 8)]);
        }
        #pragma unroll
        for (int i = 0; i < 4; ++i)
            #pragma unroll
            for (int j = 0; j < 4; ++j)
                acc[i][j] = __builtin_amdgcn_mfma_f32_16x16x32_bf16(
                    af[i], bfr[j], acc[i][j], 0, 0, 0);
        __syncthreads();
    }

    // C/D layout: col = lane&15, row = (lane>>4)*4 + reg
    const int mb = m0 + wr * 64, nb = n0 + wc * 64;
    #pragma unroll
    for (int i = 0; i < 4; ++i) {
        #pragma unroll
        for (int j = 0; j < 4; ++j) {
            const int col = nb + j * 16 + lr;
            const float bv = bias[col];
            if (OUT_MODE == 2) {
                ushort4 pk;
                #pragma unroll
                for (int q = 0; q < 4; ++q)
                    ((unsigned short*)&pk)[q] =
                        to_bf16((acc[i][j][q] + bv) * scale);
                const int r0 = mb + i * 16 + kg * 4;
                const int b = r0 >> 11, s = r0 & (SEQ - 1);
                const int h = col >> 6, d = col & (HDIM - 1);
                *reinterpret_cast<ushort4*>(
                    &((unsigned short*)outv)[(((size_t)(b * NHEADS + h)) * HDIM + d) * SEQ + s]) = pk;
            } else {
                #pragma unroll
                for (int q = 0; q < 4; ++q) {
                    const int row = mb + i * 16 + kg * 4 + q;
                    const float val = (acc[i][j][q] + bv) * scale;
                    if (OUT_MODE == 0) {
                        const int b = row >> 11, s = row & (SEQ - 1);
                        const int h = col >> 6, d = col & (HDIM - 1);
                        ((unsigned short*)outv)[(((size_t)(b * NHEADS + h)) * SEQ + s) * HDIM + d]
                            = to_bf16(val);
                    } else {
                        ((float*)outv)[(size_t)row * DMODEL + col] = val;
                    }
                }
            }
        }
    }
}

// ---------------------------------------------------------------------------
// MFMA flash attention. Grid (SEQ/64, B*H), 256 threads = 4 waves.
// Each wave owns 16 q-rows. Q,K in (B,H,S,hd) bf16 (Q pre-scaled by 0.125),
// V^T in (B,H,hd,S) bf16. K/V^T tiles (64 keys) reg-staged into padded LDS
// (row stride 72 bf16 -> uniform bank spread). In-register wave-parallel
// online softmax; P via per-wave-private LDS into A-frag layout.
// Output context bf16 (B, S, H*hd).
// ---------------------------------------------------------------------------
__global__ __launch_bounds__(256, 3) void flash_mfma(
        const unsigned short* __restrict__ Qg,
        const unsigned short* __restrict__ Kgl,
        const unsigned short* __restrict__ Vtg,
        unsigned short* __restrict__ Cctx) {
    __shared__ __align__(16) unsigned short k_s[64 * 72];
    __shared__ __align__(16) unsigned short v_s[64 * 72];   // Vt tile: [d][key]
    __shared__ __align__(16) unsigned short p_s[4 * 16 * 72];

    const int t = threadIdx.x;
    const int lane = t & 63, w = t >> 6;
    const int lr = lane & 15, kg = lane >> 4;
    const int qb = blockIdx.x, bh = blockIdx.y;
    const size_t sbase = (size_t)bh * SEQ * HDIM;   // Q/K: (B,H,S,hd)
    const size_t vtb   = (size_t)bh * HDIM * SEQ;   // Vt:  (B,H,hd,S)

    // Q fragments for this wave's 16 q-rows (held in registers for the loop)
    const int q0 = qb * 64 + w * 16;
    const bf16x8 qf0 = *reinterpret_cast<const bf16x8*>(
        &Qg[sbase + (size_t)(q0 + lr) * HDIM + kg * 8]);
    const bf16x8 qf1 = *reinterpret_cast<const bf16x8*>(
        &Qg[sbase + (size_t)(q0 + lr) * HDIM + 32 + kg * 8]);

    // staging: thread covers row sr, 16B chunks {cst, cst+4} of K and Vt
    const int sr = t >> 2, cst = t & 3;

    uint4 kr0, kr1, vr0, vr1;
    {
        const size_t ka = sbase + (size_t)sr * HDIM;
        kr0 = *reinterpret_cast<const uint4*>(&Kgl[ka + cst * 8]);
        kr1 = *reinterpret_cast<const uint4*>(&Kgl[ka + (cst + 4) * 8]);
        const size_t va = vtb + (size_t)sr * SEQ;
        vr0 = *reinterpret_cast<const uint4*>(&Vtg[va + cst * 8]);
        vr1 = *reinterpret_cast<const uint4*>(&Vtg[va + (cst + 4) * 8]);
    }

    f32x4 oa[4] = {};
    float m_run[4] = {-1e30f, -1e30f, -1e30f, -1e30f};
    float l_run[4] = {};

    const int NT = SEQ / 64;
    for (int kt = 0; kt < NT; ++kt) {
        __syncthreads();   // previous tile's LDS reads complete
        *reinterpret_cast<uint4*>(&k_s[sr * 72 + cst * 8])       = kr0;
        *reinterpret_cast<uint4*>(&k_s[sr * 72 + (cst + 4) * 8]) = kr1;
        *reinterpret_cast<uint4*>(&v_s[sr * 72 + cst * 8])       = vr0;
        *reinterpret_cast<uint4*>(&v_s[sr * 72 + (cst + 4) * 8]) = vr1;
        __syncthreads();
        if (kt + 1 < NT) {   // issue next-tile loads; latency hides under compute
            const size_t ka = sbase + (size_t)((kt + 1) * 64 + sr) * HDIM;
            kr0 = *reinterpret_cast<const uint4*>(&Kgl[ka + cst * 8]);
            kr1 = *reinterpret_cast<const uint4*>(&Kgl[ka + (cst + 4) * 8]);
            const size_t va = vtb + (size_t)sr * SEQ + (kt + 1) * 64;
            vr0 = *reinterpret_cast<const uint4*>(&Vtg[va + cst * 8]);
            vr1 = *reinterpret_cast<const uint4*>(&Vtg[va + (cst + 4) * 8]);
        }

        // ---- QK^T: S[16 q][64 keys] for this wave ----
        f32x4 st[4] = {};
        #pragma unroll
        for (int jk = 0; jk < 4; ++jk) {
            const bf16x8 kf0 = *reinterpret_cast<const bf16x8*>(
                &k_s[(jk * 16 + lr) * 72 + kg * 8]);
            const bf16x8 kf1 = *reinterpret_cast<const bf16x8*>(
                &k_s[(jk * 16 + lr) * 72 + 32 + kg * 8]);
            st[jk] = __builtin_amdgcn_mfma_f32_16x16x32_bf16(qf0, kf0, st[jk], 0, 0, 0);
            st[jk] = __builtin_amdgcn_mfma_f32_16x16x32_bf16(qf1, kf1, st[jk], 0, 0, 0);
        }

        // ---- online softmax, wave-parallel ----
        float mx[4];
        #pragma unroll
        for (int q = 0; q < 4; ++q)
            mx[q] = fmaxf(fmaxf(st[0][q], st[1][q]), fmaxf(st[2][q], st[3][q]));
        #pragma unroll
        for (int s = 1; s < 16; s <<= 1)
            #pragma unroll
            for (int q = 0; q < 4; ++q)
                mx[q] = fmaxf(mx[q], __shfl_xor(mx[q], s));

        float f[4], rs[4];
        #pragma unroll
        for (int q = 0; q < 4; ++q) {
            const float mn = fmaxf(m_run[q], mx[q]);
            f[q] = __expf(m_run[q] - mn);
            m_run[q] = mn;
            rs[q] = 0.0f;
        }
        unsigned short pb[16];
        #pragma unroll
        for (int jk = 0; jk < 4; ++jk)
            #pragma unroll
            for (int q = 0; q < 4; ++q) {
                const unsigned short pbv = to_bf16(__expf(st[jk][q] - m_run[q]));
                pb[jk * 4 + q] = pbv;
                rs[q] += bf_to_f(pbv);   // sum the bf16-rounded values (consistency)
            }
        #pragma unroll
        for (int s = 1; s < 16; s <<= 1)
            #pragma unroll
            for (int q = 0; q < 4; ++q)
                rs[q] += __shfl_xor(rs[q], s);
        #pragma unroll
        for (int q = 0; q < 4; ++q)
            l_run[q] = l_run[q] * f[q] + rs[q];
        #pragma unroll
        for (int jd = 0; jd < 4; ++jd)
            #pragma unroll
            for (int q = 0; q < 4; ++q)
                oa[jd][q] *= f[q];

        // ---- P -> per-wave LDS -> A-frag layout ----
        const int pbase = w * (16 * 72);
        #pragma unroll
        for (int jk = 0; jk < 4; ++jk)
            #pragma unroll
            for (int q = 0; q < 4; ++q)
                p_s[pbase + (kg * 4 + q) * 72 + jk * 16 + lr] = pb[jk * 4 + q];
        const bf16x8 pf0 = *reinterpret_cast<const bf16x8*>(
            &p_s[pbase + lr * 72 + kg * 8]);
        const bf16x8 pf1 = *reinterpret_cast<const bf16x8*>(
            &p_s[pbase + lr * 72 + 32 + kg * 8]);

        // ---- PV: O[16 q][64 d] += P @ V ----
        #pragma unroll
        for (int jd = 0; jd < 4; ++jd) {
            const bf16x8 vf0 = *reinterpret_cast<const bf16x8*>(
                &v_s[(jd * 16 + lr) * 72 + kg * 8]);
            const bf16x8 vf1 = *reinterpret_cast<const bf16x8*>(
                &v_s[(jd * 16 + lr) * 72 + 32 + kg * 8]);
            oa[jd] = __builtin_amdgcn_mfma_f32_16x16x32_bf16(pf0, vf0, oa[jd], 0, 0, 0);
            oa[jd] = __builtin_amdgcn_mfma_f32_16x16x32_bf16(pf1, vf1, oa[jd], 0, 0, 0);
        }
    }

    // ---- normalize + store context (B, S, H*hd) bf16 ----
    const int b = bh / NHEADS, h = bh % NHEADS;
    #pragma unroll
    for (int q = 0; q < 4; ++q) {
        const float inv = 1.0f / l_run[q];
        const int s = q0 + kg * 4 + q;
        #pragma unroll
        for (int jd = 0; jd < 4; ++jd)
            Cctx[(size_t)(b * SEQ + s) * DMODEL + h * HDIM + jd * 16 + lr] =
                to_bf16(oa[jd][q] * inv);
    }
}

// ---------------------------------------------------------------------------
extern "C" void kernel_launch(void* const* d_in, const int* in_sizes, int n_in,
                              void* d_out, int out_size, void* d_ws, size_t ws_size,
                              hipStream_t stream) {
    const float* x  = (const float*)d_in[0];
    const float* Wq = (const float*)d_in[1];
    const float* bq = (const float*)d_in[2];
    const float* Wk = (const float*)d_in[3];
    const float* bk = (const float*)d_in[4];
    const float* Wv = (const float*)d_in[5];
    const float* bv = (const float*)d_in[6];
    const float* Wo = (const float*)d_in[7];
    const float* bo = (const float*)d_in[8];
    float* out = (float*)d_out;

    const size_t MD = (size_t)MROWS * DMODEL;    // 3,145,728
    const size_t W2 = (size_t)DMODEL * DMODEL;   // 589,824
    unsigned short* u = (unsigned short*)d_ws;
    unsigned short* x_bf   = u;            // bf16 x (M x 768)
    unsigned short* q_bf   = u + MD;       // bf16 Q (B,H,S,hd), pre-scaled
    unsigned short* k_bf   = u + 2 * MD;   // bf16 K (B,H,S,hd)
    unsigned short* vt_bf  = u + 3 * MD;   // bf16 V^T (B,H,hd,S)
    unsigned short* c_bf   = u + 4 * MD;   // bf16 context (B,S,768)
    unsigned short* wt_all = u + 5 * MD;   // Wq^T,Wk^T,Wv^T bf16 [n][k]
    unsigned short* wot    = wt_all + 3 * W2;
    // total: (5*MD + 4*W2)*2B = 36.2 MB

    cvt_x<<<(int)(MD / 4 + 255) / 256, 256, 0, stream>>>(x, x_bf, (int)(MD / 4));
    cvt_wT<<<dim3(24, 24, 4), 256, 0, stream>>>(Wq, Wk, Wv, Wo, wt_all, wot);

    dim3 gg(DMODEL / 128, MROWS / 128);   // (6, 32)
    gemm_mfma<0><<<gg, 256, 0, stream>>>(x_bf, wt_all,          bq, q_bf, 0.125f);
    gemm_mfma<0><<<gg, 256, 0, stream>>>(x_bf, wt_all + W2,     bk, k_bf, 1.0f);
    gemm_mfma<2><<<gg, 256, 0, stream>>>(x_bf, wt_all + 2 * W2, bv, vt_bf, 1.0f);

    dim3 ga(SEQ / 64, BATCH * NHEADS);    // (32, 24)
    flash_mfma<<<ga, 256, 0, stream>>>(q_bf, k_bf, vt_bf, c_bf);

    gemm_mfma<1><<<gg, 256, 0, stream>>>(c_bf, wot, bo, out, 1.0f);
}

// Round 6
// 214.657 us; speedup vs baseline: 4.2629x; 1.1763x over previous
//
#include <hip/hip_runtime.h>
#include <hip/hip_bf16.h>

#define NHEADS 12
#define HDIM 64
#define BATCH 2
#define SEQ 2048
#define DMODEL 768
#define MROWS (BATCH * SEQ)   // 4096

typedef __bf16  bf16x8 __attribute__((ext_vector_type(8)));
typedef float   f32x4  __attribute__((ext_vector_type(4)));

__device__ inline unsigned short to_bf16(float f) {
    union { float f; unsigned u; } x; x.f = f;
    const unsigned r = x.u + 0x7FFFu + ((x.u >> 16) & 1u);   // RNE
    return (unsigned short)(r >> 16);
}
__device__ inline unsigned pack_bf16x2(float a, float b) {
    const __hip_bfloat162 h = __float22bfloat162_rn(float2{a, b});
    union { __hip_bfloat162 h; unsigned u; } c; c.h = h; return c.u;
}

// async global->LDS, 16B per lane, dest = wave-uniform base + lane*16
#define GLDS16(gsrc, ldst)                                                    \
    __builtin_amdgcn_global_load_lds(                                         \
        (const __attribute__((address_space(1))) void*)(gsrc),                \
        (__attribute__((address_space(3))) void*)(ldst), 16, 0, 0)

// ---------------------------------------------------------------------------
// cvt_x: fp32 -> bf16 elementwise, float4-vectorized
// ---------------------------------------------------------------------------
__global__ __launch_bounds__(256) void cvt_x(const float* __restrict__ in,
                                             unsigned short* __restrict__ out,
                                             int n4) {
    const int i = blockIdx.x * 256 + threadIdx.x;
    if (i < n4) {
        const float4 v = reinterpret_cast<const float4*>(in)[i];
        ushort4 o;
        o.x = to_bf16(v.x); o.y = to_bf16(v.y);
        o.z = to_bf16(v.z); o.w = to_bf16(v.w);
        reinterpret_cast<ushort4*>(out)[i] = o;
    }
}

// ---------------------------------------------------------------------------
// cvt_wT: W (768x768 fp32, [k][n]) -> Wt (768x768 bf16, [n][k]), 4 matrices.
// Wq/Wk/Wv land contiguous in wt_all => one 2304-row B matrix for fused QKV.
// ---------------------------------------------------------------------------
__global__ __launch_bounds__(256) void cvt_wT(const float* __restrict__ Wq,
                                              const float* __restrict__ Wk,
                                              const float* __restrict__ Wv,
                                              const float* __restrict__ Wo,
                                              unsigned short* __restrict__ wt_all,
                                              unsigned short* __restrict__ wot) {
    const int z = blockIdx.z;
    const float* W = (z == 0) ? Wq : (z == 1) ? Wk : (z == 2) ? Wv : Wo;
    unsigned short* out = (z < 3) ? (wt_all + (size_t)z * DMODEL * DMODEL) : wot;

    __shared__ float tile[32][33];
    const int tx = threadIdx.x & 31, ty = threadIdx.x >> 5;
    const int nbase = blockIdx.x * 32, kbase = blockIdx.y * 32;

    #pragma unroll
    for (int p = 0; p < 4; ++p) {
        const int r = ty + p * 8;
        tile[r][tx] = W[(size_t)(kbase + r) * DMODEL + nbase + tx];
    }
    __syncthreads();
    #pragma unroll
    for (int p = 0; p < 4; ++p) {
        const int r = ty + p * 8;
        out[(size_t)(nbase + r) * DMODEL + kbase + tx] = to_bf16(tile[tx][r]);
    }
}

// ---------------------------------------------------------------------------
// Fused QKV GEMM: A (4096 x 768 bf16) @ Wt^T (Wt: 2304 x 768 bf16 [n][k]).
// seg = n/768 selects {Q scatter (B,H,S,hd), K scatter, V^T scatter (B,H,hd,S)}.
// Q segment scaled by 0.125 ((xW+b)*scale). 128x128 tile, BK=32, 4 waves.
// ---------------------------------------------------------------------------
__global__ __launch_bounds__(256) void gemm_qkv(const unsigned short* __restrict__ A,
                                                const unsigned short* __restrict__ Wt,
                                                const float* __restrict__ bq,
                                                const float* __restrict__ bk,
                                                const float* __restrict__ bv,
                                                unsigned short* __restrict__ q_bf,
                                                unsigned short* __restrict__ k_bf,
                                                unsigned short* __restrict__ vt_bf) {
    constexpr int K = DMODEL;
    __shared__ unsigned short As[128 * 32];
    __shared__ unsigned short Bs[128 * 32];

    const int t = threadIdx.x;
    const int lane = t & 63;
    const int w = t >> 6, wr = w >> 1, wc = w & 1;
    const int m0 = blockIdx.y * 128, n0 = blockIdx.x * 128;
    const int lr = lane & 15;
    const int kg = lane >> 4;

    const int row0 = t >> 2,        cp0 = t & 3;
    const int row1 = (t + 256) >> 2, cp1 = t & 3;
    const int c0 = cp0 ^ ((row0 >> 1) & 3);
    const int c1 = cp1 ^ ((row1 >> 1) & 3);
    unsigned short* asd0 = &As[(w * 64) * 8];
    unsigned short* asd1 = &As[(256 + w * 64) * 8];
    unsigned short* bsd0 = &Bs[(w * 64) * 8];
    unsigned short* bsd1 = &Bs[(256 + w * 64) * 8];

    f32x4 acc[4][4] = {};

    for (int k0 = 0; k0 < K; k0 += 32) {
        GLDS16(A  + (size_t)(m0 + row0) * K + k0 + c0 * 8, asd0);
        GLDS16(A  + (size_t)(m0 + row1) * K + k0 + c1 * 8, asd1);
        GLDS16(Wt + (size_t)(n0 + row0) * K + k0 + c0 * 8, bsd0);
        GLDS16(Wt + (size_t)(n0 + row1) * K + k0 + c1 * 8, bsd1);
        __syncthreads();

        bf16x8 af[4], bfr[4];
        #pragma unroll
        for (int i = 0; i < 4; ++i) {
            const int ar = wr * 64 + i * 16 + lr;
            af[i] = *reinterpret_cast<const bf16x8*>(
                &As[ar * 32 + ((kg ^ ((ar >> 1) & 3)) * 8)]);
            const int br = wc * 64 + i * 16 + lr;
            bfr[i] = *reinterpret_cast<const bf16x8*>(
                &Bs[br * 32 + ((kg ^ ((br >> 1) & 3)) * 8)]);
        }
        #pragma unroll
        for (int i = 0; i < 4; ++i)
            #pragma unroll
            for (int j = 0; j < 4; ++j)
                acc[i][j] = __builtin_amdgcn_mfma_f32_16x16x32_bf16(
                    af[i], bfr[j], acc[i][j], 0, 0, 0);
        __syncthreads();
    }

    // epilogue: seg is block-uniform (768 % 128 == 0)
    const int seg = n0 / DMODEL;
    const float scale = (seg == 0) ? 0.125f : 1.0f;
    const float* bias = (seg == 0) ? bq : (seg == 1) ? bk : bv;
    const int mb = m0 + wr * 64, nb = n0 - seg * DMODEL + wc * 64;

    #pragma unroll
    for (int i = 0; i < 4; ++i) {
        #pragma unroll
        for (int j = 0; j < 4; ++j) {
            const int cl = nb + j * 16 + lr;       // column within matrix
            const float bv_ = bias[cl];
            const int h = cl >> 6, d = cl & (HDIM - 1);
            if (seg < 2) {
                unsigned short* dst = (seg == 0) ? q_bf : k_bf;
                #pragma unroll
                for (int q = 0; q < 4; ++q) {
                    const int row = mb + i * 16 + kg * 4 + q;
                    const int b = row >> 11, s = row & (SEQ - 1);
                    dst[(((size_t)(b * NHEADS + h)) * SEQ + s) * HDIM + d] =
                        to_bf16((acc[i][j][q] + bv_) * scale);
                }
            } else {
                ushort4 pk;
                #pragma unroll
                for (int q = 0; q < 4; ++q)
                    ((unsigned short*)&pk)[q] = to_bf16(acc[i][j][q] + bv_);
                const int r0 = mb + i * 16 + kg * 4;
                const int b = r0 >> 11, s = r0 & (SEQ - 1);
                *reinterpret_cast<ushort4*>(
                    &vt_bf[(((size_t)(b * NHEADS + h)) * HDIM + d) * SEQ + s]) = pk;
            }
        }
    }
}

// ---------------------------------------------------------------------------
// Out-projection GEMM: C = A (4096 x 768 bf16) @ Wo^T + bo, fp32 row-major.
// ---------------------------------------------------------------------------
__global__ __launch_bounds__(256) void gemm_out(const unsigned short* __restrict__ A,
                                                const unsigned short* __restrict__ Bt,
                                                const float* __restrict__ bias,
                                                float* __restrict__ out) {
    constexpr int K = DMODEL;
    __shared__ unsigned short As[128 * 32];
    __shared__ unsigned short Bs[128 * 32];

    const int t = threadIdx.x;
    const int lane = t & 63;
    const int w = t >> 6, wr = w >> 1, wc = w & 1;
    const int m0 = blockIdx.y * 128, n0 = blockIdx.x * 128;
    const int lr = lane & 15;
    const int kg = lane >> 4;

    const int row0 = t >> 2,        cp0 = t & 3;
    const int row1 = (t + 256) >> 2, cp1 = t & 3;
    const int c0 = cp0 ^ ((row0 >> 1) & 3);
    const int c1 = cp1 ^ ((row1 >> 1) & 3);
    unsigned short* asd0 = &As[(w * 64) * 8];
    unsigned short* asd1 = &As[(256 + w * 64) * 8];
    unsigned short* bsd0 = &Bs[(w * 64) * 8];
    unsigned short* bsd1 = &Bs[(256 + w * 64) * 8];

    f32x4 acc[4][4] = {};

    for (int k0 = 0; k0 < K; k0 += 32) {
        GLDS16(A  + (size_t)(m0 + row0) * K + k0 + c0 * 8, asd0);
        GLDS16(A  + (size_t)(m0 + row1) * K + k0 + c1 * 8, asd1);
        GLDS16(Bt + (size_t)(n0 + row0) * K + k0 + c0 * 8, bsd0);
        GLDS16(Bt + (size_t)(n0 + row1) * K + k0 + c1 * 8, bsd1);
        __syncthreads();

        bf16x8 af[4], bfr[4];
        #pragma unroll
        for (int i = 0; i < 4; ++i) {
            const int ar = wr * 64 + i * 16 + lr;
            af[i] = *reinterpret_cast<const bf16x8*>(
                &As[ar * 32 + ((kg ^ ((ar >> 1) & 3)) * 8)]);
            const int br = wc * 64 + i * 16 + lr;
            bfr[i] = *reinterpret_cast<const bf16x8*>(
                &Bs[br * 32 + ((kg ^ ((br >> 1) & 3)) * 8)]);
        }
        #pragma unroll
        for (int i = 0; i < 4; ++i)
            #pragma unroll
            for (int j = 0; j < 4; ++j)
                acc[i][j] = __builtin_amdgcn_mfma_f32_16x16x32_bf16(
                    af[i], bfr[j], acc[i][j], 0, 0, 0);
        __syncthreads();
    }

    const int mb = m0 + wr * 64, nb = n0 + wc * 64;
    #pragma unroll
    for (int i = 0; i < 4; ++i) {
        #pragma unroll
        for (int j = 0; j < 4; ++j) {
            const int col = nb + j * 16 + lr;
            const float bv = bias[col];
            #pragma unroll
            for (int q = 0; q < 4; ++q) {
                const int row = mb + i * 16 + kg * 4 + q;
                out[(size_t)row * DMODEL + col] = acc[i][j][q] + bv;
            }
        }
    }
}

// ---------------------------------------------------------------------------
// MFMA flash attention. Grid (SEQ/64, B*H), 256 threads = 4 waves.
// Each wave owns 16 q-rows. Q,K (B,H,S,hd) bf16 (Q pre-scaled), V^T (B,H,hd,S).
// Online softmax: max via shfl; denominator via ones-column MFMA into l_acc
// (exactly consistent with PV numerator). P packed with v_cvt_pk_bf16_f32.
// ---------------------------------------------------------------------------
__global__ __launch_bounds__(256, 4) void flash_mfma(
        const unsigned short* __restrict__ Qg,
        const unsigned short* __restrict__ Kgl,
        const unsigned short* __restrict__ Vtg,
        unsigned short* __restrict__ Cctx) {
    __shared__ __align__(16) unsigned short k_s[64 * 72];
    __shared__ __align__(16) unsigned short v_s[64 * 72];   // Vt tile: [d][key]
    __shared__ __align__(16) unsigned short p_s[4 * 16 * 72];

    const int t = threadIdx.x;
    const int lane = t & 63, w = t >> 6;
    const int lr = lane & 15, kg = lane >> 4;
    const int qb = blockIdx.x, bh = blockIdx.y;
    const size_t sbase = (size_t)bh * SEQ * HDIM;   // Q/K: (B,H,S,hd)
    const size_t vtb   = (size_t)bh * HDIM * SEQ;   // Vt:  (B,H,hd,S)

    const int q0 = qb * 64 + w * 16;
    const bf16x8 qf0 = *reinterpret_cast<const bf16x8*>(
        &Qg[sbase + (size_t)(q0 + lr) * HDIM + kg * 8]);
    const bf16x8 qf1 = *reinterpret_cast<const bf16x8*>(
        &Qg[sbase + (size_t)(q0 + lr) * HDIM + 32 + kg * 8]);

    bf16x8 ones;
    #pragma unroll
    for (int i = 0; i < 8; ++i) ones[i] = (__bf16)1.0f;

    const int sr = t >> 2, cst = t & 3;

    uint4 kr0, kr1, vr0, vr1;
    {
        const size_t ka = sbase + (size_t)sr * HDIM;
        kr0 = *reinterpret_cast<const uint4*>(&Kgl[ka + cst * 8]);
        kr1 = *reinterpret_cast<const uint4*>(&Kgl[ka + (cst + 4) * 8]);
        const size_t va = vtb + (size_t)sr * SEQ;
        vr0 = *reinterpret_cast<const uint4*>(&Vtg[va + cst * 8]);
        vr1 = *reinterpret_cast<const uint4*>(&Vtg[va + (cst + 4) * 8]);
    }

    f32x4 oa[4] = {};
    f32x4 l_acc = {};
    float m_run[4] = {-1e30f, -1e30f, -1e30f, -1e30f};

    const int NT = SEQ / 64;
    for (int kt = 0; kt < NT; ++kt) {
        __syncthreads();
        *reinterpret_cast<uint4*>(&k_s[sr * 72 + cst * 8])       = kr0;
        *reinterpret_cast<uint4*>(&k_s[sr * 72 + (cst + 4) * 8]) = kr1;
        *reinterpret_cast<uint4*>(&v_s[sr * 72 + cst * 8])       = vr0;
        *reinterpret_cast<uint4*>(&v_s[sr * 72 + (cst + 4) * 8]) = vr1;
        __syncthreads();
        if (kt + 1 < NT) {
            const size_t ka = sbase + (size_t)((kt + 1) * 64 + sr) * HDIM;
            kr0 = *reinterpret_cast<const uint4*>(&Kgl[ka + cst * 8]);
            kr1 = *reinterpret_cast<const uint4*>(&Kgl[ka + (cst + 4) * 8]);
            const size_t va = vtb + (size_t)sr * SEQ + (kt + 1) * 64;
            vr0 = *reinterpret_cast<const uint4*>(&Vtg[va + cst * 8]);
            vr1 = *reinterpret_cast<const uint4*>(&Vtg[va + (cst + 4) * 8]);
        }

        // ---- QK^T: S[16 q][64 keys] for this wave ----
        f32x4 st[4] = {};
        __builtin_amdgcn_s_setprio(1);
        #pragma unroll
        for (int jk = 0; jk < 4; ++jk) {
            const bf16x8 kf0 = *reinterpret_cast<const bf16x8*>(
                &k_s[(jk * 16 + lr) * 72 + kg * 8]);
            const bf16x8 kf1 = *reinterpret_cast<const bf16x8*>(
                &k_s[(jk * 16 + lr) * 72 + 32 + kg * 8]);
            st[jk] = __builtin_amdgcn_mfma_f32_16x16x32_bf16(qf0, kf0, st[jk], 0, 0, 0);
            st[jk] = __builtin_amdgcn_mfma_f32_16x16x32_bf16(qf1, kf1, st[jk], 0, 0, 0);
        }
        __builtin_amdgcn_s_setprio(0);

        // ---- online softmax (max only; sum via ones-MFMA below) ----
        float mx[4];
        #pragma unroll
        for (int q = 0; q < 4; ++q)
            mx[q] = fmaxf(fmaxf(st[0][q], st[1][q]), fmaxf(st[2][q], st[3][q]));
        #pragma unroll
        for (int s = 1; s < 16; s <<= 1)
            #pragma unroll
            for (int q = 0; q < 4; ++q)
                mx[q] = fmaxf(mx[q], __shfl_xor(mx[q], s));

        float f[4];
        #pragma unroll
        for (int q = 0; q < 4; ++q) {
            const float mn = fmaxf(m_run[q], mx[q]);
            f[q] = __expf(m_run[q] - mn);
            m_run[q] = mn;
        }

        // exp + pack pairs (v_cvt_pk_bf16_f32 via intrinsic)
        unsigned pk01[4], pk23[4];
        #pragma unroll
        for (int jk = 0; jk < 4; ++jk) {
            pk01[jk] = pack_bf16x2(__expf(st[jk][0] - m_run[0]),
                                   __expf(st[jk][1] - m_run[1]));
            pk23[jk] = pack_bf16x2(__expf(st[jk][2] - m_run[2]),
                                   __expf(st[jk][3] - m_run[3]));
        }

        // rescale O and l
        #pragma unroll
        for (int q = 0; q < 4; ++q) l_acc[q] *= f[q];
        #pragma unroll
        for (int jd = 0; jd < 4; ++jd)
            #pragma unroll
            for (int q = 0; q < 4; ++q)
                oa[jd][q] *= f[q];

        // ---- P -> per-wave LDS -> A-frag layout ----
        const int pbase = w * (16 * 72);
        #pragma unroll
        for (int jk = 0; jk < 4; ++jk) {
            p_s[pbase + (kg * 4 + 0) * 72 + jk * 16 + lr] = (unsigned short)(pk01[jk] & 0xFFFFu);
            p_s[pbase + (kg * 4 + 1) * 72 + jk * 16 + lr] = (unsigned short)(pk01[jk] >> 16);
            p_s[pbase + (kg * 4 + 2) * 72 + jk * 16 + lr] = (unsigned short)(pk23[jk] & 0xFFFFu);
            p_s[pbase + (kg * 4 + 3) * 72 + jk * 16 + lr] = (unsigned short)(pk23[jk] >> 16);
        }
        const bf16x8 pf0 = *reinterpret_cast<const bf16x8*>(
            &p_s[pbase + lr * 72 + kg * 8]);
        const bf16x8 pf1 = *reinterpret_cast<const bf16x8*>(
            &p_s[pbase + lr * 72 + 32 + kg * 8]);

        // ---- PV + l-sum: O += P @ V ; l += P @ 1 ----
        __builtin_amdgcn_s_setprio(1);
        l_acc = __builtin_amdgcn_mfma_f32_16x16x32_bf16(pf0, ones, l_acc, 0, 0, 0);
        l_acc = __builtin_amdgcn_mfma_f32_16x16x32_bf16(pf1, ones, l_acc, 0, 0, 0);
        #pragma unroll
        for (int jd = 0; jd < 4; ++jd) {
            const bf16x8 vf0 = *reinterpret_cast<const bf16x8*>(
                &v_s[(jd * 16 + lr) * 72 + kg * 8]);
            const bf16x8 vf1 = *reinterpret_cast<const bf16x8*>(
                &v_s[(jd * 16 + lr) * 72 + 32 + kg * 8]);
            oa[jd] = __builtin_amdgcn_mfma_f32_16x16x32_bf16(pf0, vf0, oa[jd], 0, 0, 0);
            oa[jd] = __builtin_amdgcn_mfma_f32_16x16x32_bf16(pf1, vf1, oa[jd], 0, 0, 0);
        }
        __builtin_amdgcn_s_setprio(0);
    }

    // ---- normalize + store context (B, S, H*hd) bf16 ----
    const int b = bh / NHEADS, h = bh % NHEADS;
    #pragma unroll
    for (int q = 0; q < 4; ++q) {
        const float inv = 1.0f / l_acc[q];
        const int s = q0 + kg * 4 + q;
        #pragma unroll
        for (int jd = 0; jd < 4; ++jd)
            Cctx[(size_t)(b * SEQ + s) * DMODEL + h * HDIM + jd * 16 + lr] =
                to_bf16(oa[jd][q] * inv);
    }
}

// ---------------------------------------------------------------------------
extern "C" void kernel_launch(void* const* d_in, const int* in_sizes, int n_in,
                              void* d_out, int out_size, void* d_ws, size_t ws_size,
                              hipStream_t stream) {
    const float* x  = (const float*)d_in[0];
    const float* Wq = (const float*)d_in[1];
    const float* bq = (const float*)d_in[2];
    const float* Wk = (const float*)d_in[3];
    const float* bk = (const float*)d_in[4];
    const float* Wv = (const float*)d_in[5];
    const float* bv = (const float*)d_in[6];
    const float* Wo = (const float*)d_in[7];
    const float* bo = (const float*)d_in[8];
    float* out = (float*)d_out;

    const size_t MD = (size_t)MROWS * DMODEL;    // 3,145,728
    const size_t W2 = (size_t)DMODEL * DMODEL;   // 589,824
    unsigned short* u = (unsigned short*)d_ws;
    unsigned short* x_bf   = u;            // bf16 x (M x 768)
    unsigned short* q_bf   = u + MD;       // bf16 Q (B,H,S,hd), pre-scaled
    unsigned short* k_bf   = u + 2 * MD;   // bf16 K (B,H,S,hd)
    unsigned short* vt_bf  = u + 3 * MD;   // bf16 V^T (B,H,hd,S)
    unsigned short* c_bf   = u + 4 * MD;   // bf16 context (B,S,768)
    unsigned short* wt_all = u + 5 * MD;   // [Wq^T;Wk^T;Wv^T] bf16 (2304 x 768)
    unsigned short* wot    = wt_all + 3 * W2;
    // total: (5*MD + 4*W2)*2B = 36.2 MB

    cvt_x<<<(int)(MD / 4 + 255) / 256, 256, 0, stream>>>(x, x_bf, (int)(MD / 4));
    cvt_wT<<<dim3(24, 24, 4), 256, 0, stream>>>(Wq, Wk, Wv, Wo, wt_all, wot);

    dim3 gq(3 * DMODEL / 128, MROWS / 128);   // (18, 32) = 576 blocks
    gemm_qkv<<<gq, 256, 0, stream>>>(x_bf, wt_all, bq, bk, bv, q_bf, k_bf, vt_bf);

    dim3 ga(SEQ / 64, BATCH * NHEADS);        // (32, 24)
    flash_mfma<<<ga, 256, 0, stream>>>(q_bf, k_bf, vt_bf, c_bf);

    dim3 gg(DMODEL / 128, MROWS / 128);       // (6, 32)
    gemm_out<<<gg, 256, 0, stream>>>(c_bf, wot, bo, out);
}